// Round 13
// baseline (951.607 us; speedup 1.0000x reference)
//
#include <hip/hip_runtime.h>
#include <stdint.h>

typedef __attribute__((ext_vector_type(8))) short bf16x8;
typedef __attribute__((ext_vector_type(4))) float f32x4;

#define HW    36864   // 192*192
#define CCH   384
#define NPIX  73728   // 2 batches * HW
#define W2    147456  // 384*384
#define NPAD  1280    // padded QKV output channels (1152 -> 1280)
#define WTF   491520  // NPAD*384, per-frame weight panel elems

__device__ __forceinline__ unsigned short f2bf(float f) {
  unsigned u = __builtin_bit_cast(unsigned, f);
  u += 0x7FFFu + ((u >> 16) & 1u);
  return (unsigned short)(u >> 16);
}

typedef const unsigned int __attribute__((address_space(1)))* gas1_t;
typedef unsigned int __attribute__((address_space(3)))* las3_t;
__device__ __forceinline__ void gload16(const void* g, void* l) {
  __builtin_amdgcn_global_load_lds((gas1_t)g, (las3_t)l, 16, 0, 0);
}

// ---------------- prep kernels ----------------

// Per-frame padded weight panel: frame f rows = [wq_f | wk_{1-f} | wv_{1-f} | 0].
__global__ void k_wt(const float* __restrict__ w0, const float* __restrict__ w1,
                     const float* __restrict__ w2, const float* __restrict__ w3,
                     const float* __restrict__ w4, const float* __restrict__ w5,
                     unsigned short* __restrict__ wt) {
  int idx = blockIdx.x * 256 + threadIdx.x;   // 0..147455
  int w = blockIdx.y;
  const float* W;
  switch (w) { case 0: W = w0; break; case 1: W = w1; break;
               case 2: W = w2; break; case 3: W = w3; break;
               case 4: W = w4; break; default: W = w5; break; }
  const int fmap[6]    = {0, 1, 1, 1, 0, 0};
  const int basemap[6] = {0, 384, 768, 0, 384, 768};
  int c = idx / 384, d = idx % 384;
  wt[(size_t)fmap[w] * WTF + (size_t)(basemap[w] + d) * 384 + c] =
      f2bf(W[(size_t)c * 384 + d]);
}

__global__ void k_pad(unsigned short* __restrict__ wt) {
  int idx = blockIdx.x * 256 + threadIdx.x;  // 0..98303
  int f = idx / 49152, rem = idx % 49152;
  wt[(size_t)f * WTF + 1152 * 384 + rem] = 0;
}

__global__ void k_wf(const float* __restrict__ wo1, const float* __restrict__ pj1,
                     const float* __restrict__ wo2, const float* __restrict__ pj2,
                     unsigned short* __restrict__ wfT) {
  int idx = blockIdx.x * 256 + threadIdx.x;
  int s = blockIdx.y;
  const float* wo = s ? wo2 : wo1;
  const float* pj = s ? pj2 : pj1;
  int d = idx / 384, e = idx % 384;
  float acc = 0.f;
  for (int c = 0; c < 384; ++c) acc += pj[d * 384 + c] * wo[e * 384 + c];
  wfT[(size_t)s * W2 + (size_t)d * 384 + e] = f2bf(acc);
}

__global__ void k_bf(const float* __restrict__ bo1, const float* __restrict__ pj1,
                     const float* __restrict__ pb1, const float* __restrict__ bo2,
                     const float* __restrict__ pj2, const float* __restrict__ pb2,
                     float* __restrict__ bfused) {
  int t = threadIdx.x;  // 0..767
  int s = t / 384, d = t % 384;
  const float* bo = s ? bo2 : bo1;
  const float* pj = s ? pj2 : pj1;
  const float* pb = s ? pb2 : pb1;
  float acc = pb[d];
  for (int c = 0; c < 384; ++c) acc += pj[d * 384 + c] * bo[c];
  bfused[t] = acc;
}

// xbf[t][b][p][c] = bf16( x[b][c][t][p] )
__global__ __launch_bounds__(256) void k_tx(const float* __restrict__ x,
                                            unsigned short* __restrict__ xbf) {
  __shared__ float tile[64][65];
  int p0 = blockIdx.x * 64;
  int c0 = blockIdx.y * 64;
  int bt = blockIdx.z;  // b*2 + t
  int b = bt >> 1, t = bt & 1;
  int tid = threadIdx.x;
  int cl = tid >> 2;
  int pq = (tid & 3) * 4;
  const float* src = x + (((size_t)b * CCH + (c0 + cl)) * 2 + t) * HW + p0;
#pragma unroll
  for (int i = 0; i < 4; ++i) {
    int p_l = pq + i * 16;
    float4 v = *reinterpret_cast<const float4*>(src + p_l);
    tile[cl][p_l + 0] = v.x; tile[cl][p_l + 1] = v.y;
    tile[cl][p_l + 2] = v.z; tile[cl][p_l + 3] = v.w;
  }
  __syncthreads();
  int pl = tid >> 2;
  int cq = (tid & 3) * 16;
  unsigned short* dst = xbf + ((size_t)(t * 2 + b) * HW + p0 + pl) * CCH + c0 + cq;
  bf16x8 o0, o1;
#pragma unroll
  for (int j = 0; j < 8; ++j) o0[j] = (short)f2bf(tile[cq + j][pl]);
#pragma unroll
  for (int j = 0; j < 8; ++j) o1[j] = (short)f2bf(tile[cq + 8 + j][pl]);
  *reinterpret_cast<bf16x8*>(dst) = o0;
  *reinterpret_cast<bf16x8*>(dst + 8) = o1;
}

// ---- QKV GEMM: persistent m-loop, 256x256x64 tiles, both frames ----
// Grid (5, 48) = 240 blocks (single round on 256 CUs). Block owns one
// n-panel (256 cols) x 12 m-tiles (3072 pixel rows); 72-K-tile continuous
// pipeline (tile (mt,5) stages (mt+1,0); buffer parity kt&1 is continuous).
// Per K-tile: 4 phases a 16 MFMA, 24 ds_read_b128/wave (bf_lo/bf_hi resident),
// counted vmcnt(4) end-P1 / vmcnt(2) end-P3 (r12-proven ledger).
__global__ __launch_bounds__(512) void gemm_qkv(
    const unsigned short* __restrict__ xbf,
    const unsigned short* __restrict__ wt,
    unsigned short* __restrict__ qb0,
    unsigned short* __restrict__ qb1,
    unsigned short* __restrict__ kvb0,
    unsigned short* __restrict__ kvb1,
    float oscale) {
  __shared__ __align__(16) unsigned short Lsh[2][32768];  // A 0..16383 | B 16384..32767
  const int tid = threadIdx.x;
  const int lane = tid & 63;
  const int wid = tid >> 6;
  const int wr = wid >> 2, wc = wid & 3;   // 2 M-waves x 4 N-waves
  const int r15 = lane & 15, g = lane >> 4;
  const int rsw = r15 & 7;

  // XCD-aware swizzle (nwg = 240, %8 == 0)
  const int gx = gridDim.x;
  const int nwg = gx * gridDim.y;
  const int bid = blockIdx.x + blockIdx.y * gx;
  const int chunk = nwg >> 3;
  const int l = (bid & 7) * chunk + (bid >> 3);
  const int bx = l % gx, by = l / gx;

  const int f = (by >= 24) ? 1 : 0;
  const int mg = by - f * 24;           // m-group 0..23 within frame
  const int mbase = mg * 3072;          // frame-local pixel row base (12 m-tiles)
  const int n0 = bx * 256;

  const unsigned short* A  = xbf + (size_t)f * NPIX * 384;
  const unsigned short* Bt = wt + (size_t)f * WTF;
  unsigned short* Cq  = f ? qb1 : qb0;
  unsigned short* Ckv = f ? kvb0 : kvb1;

  const int gsl = (tid & 7) ^ ((tid >> 3) & 7);
  const unsigned short* srcA = A + (size_t)(mbase + (tid >> 3)) * 384 + gsl * 8;
  const unsigned short* srcB = Bt + (size_t)(n0 + (tid >> 3)) * 384 + gsl * 8;

  f32x4 acc[8][4];
  f32x4 zero4 = {0.f, 0.f, 0.f, 0.f};
#pragma unroll
  for (int a = 0; a < 8; ++a)
#pragma unroll
    for (int b = 0; b < 4; ++b) acc[a][b] = zero4;

#define SAq(buf, src, ko, q) gload16((src) + (size_t)(q) * 64 * 384 + (ko), \
                                     &Lsh[(buf)][tid * 8 + (q) * 4096])
#define SBq(buf, ko, q) gload16(srcB + (size_t)(q) * 64 * 384 + (ko), \
                                &Lsh[(buf)][16384 + tid * 8 + (q) * 4096])

  bf16x8 af[4][2], bf_lo[2][2], bf_hi[2][2];
#define LDA(buf, mh) do {                                                        \
    _Pragma("unroll")                                                            \
    for (int a = 0; a < 4; ++a) {                                                \
      int row = wr * 128 + (mh) * 64 + a * 16 + r15;                             \
      af[a][0] = *(const bf16x8*)&Lsh[(buf)][row * 64 + ((0 + g) ^ rsw) * 8];    \
      af[a][1] = *(const bf16x8*)&Lsh[(buf)][row * 64 + ((4 + g) ^ rsw) * 8];    \
    } } while (0)
#define LDB(buf, nh, DST) do {                                                   \
    _Pragma("unroll")                                                            \
    for (int b = 0; b < 2; ++b) {                                                \
      int row = wc * 64 + (nh) * 32 + b * 16 + r15;                              \
      DST[b][0] = *(const bf16x8*)&Lsh[(buf)][16384 + row * 64 + ((0 + g) ^ rsw) * 8];\
      DST[b][1] = *(const bf16x8*)&Lsh[(buf)][16384 + row * 64 + ((4 + g) ^ rsw) * 8];\
    } } while (0)
#define MM(mh, nh, BF) do {                                                      \
    __builtin_amdgcn_s_setprio(1);                                               \
    _Pragma("unroll")                                                            \
    for (int a = 0; a < 4; ++a)                                                  \
      _Pragma("unroll")                                                          \
      for (int b = 0; b < 2; ++b) {                                              \
        acc[(mh)*4+a][(nh)*2+b] = __builtin_amdgcn_mfma_f32_16x16x32_bf16(       \
            af[a][0], BF[b][0], acc[(mh)*4+a][(nh)*2+b], 0, 0, 0);               \
        acc[(mh)*4+a][(nh)*2+b] = __builtin_amdgcn_mfma_f32_16x16x32_bf16(       \
            af[a][1], BF[b][1], acc[(mh)*4+a][(nh)*2+b], 0, 0, 0);               \
      }                                                                          \
    __builtin_amdgcn_s_setprio(0);                                               \
  } while (0)

#define BAR() __builtin_amdgcn_s_barrier()
#define LGKM0() asm volatile("s_waitcnt lgkmcnt(0)" ::: "memory")

  // Steady tile: stage next tile (ASRC, KO2) split across phases.
  // Ledger (entry: 2 A-odd loads of this tile in flight):
  //  P0 +SB(q0,q1)->4; P1 +SB(q2,q3)->6, vmcnt(4) retires A-odd(this);
  //  P2 +SA(q0,q2)->6; P3 +SA(q1,q3)->8, vmcnt(2) retires B+A-even(next).
#define TILE_STEADY(kt, ASRC, KO2) do {                                       \
    constexpr int c_ = (kt) & 1, s_ = c_ ^ 1;                                 \
    LDA(c_, 0); LDB(c_, 0, bf_lo);                                            \
    SBq(s_, (KO2), 0); SBq(s_, (KO2), 1);                                     \
    BAR(); LGKM0(); MM(0, 0, bf_lo); BAR();                                   \
    LDB(c_, 1, bf_hi);                                                        \
    SBq(s_, (KO2), 2); SBq(s_, (KO2), 3);                                     \
    BAR(); LGKM0(); MM(0, 1, bf_hi);                                          \
    asm volatile("s_waitcnt vmcnt(4)" ::: "memory");                          \
    BAR();                                                                    \
    LDA(c_, 1);                                                               \
    SAq(s_, (ASRC), (KO2), 0); SAq(s_, (ASRC), (KO2), 2);                     \
    BAR(); LGKM0(); MM(1, 1, bf_hi); BAR();                                   \
    SAq(s_, (ASRC), (KO2), 1); SAq(s_, (ASRC), (KO2), 3);                     \
    BAR(); MM(1, 0, bf_lo);                                                   \
    asm volatile("s_waitcnt vmcnt(2)" ::: "memory");                          \
    BAR();                                                                    \
  } while (0)

  // prologue: stage tile (0,0); order B q0..3, A-even, A-odd; leave A-odd in flight
  SBq(0, 0, 0); SBq(0, 0, 1); SBq(0, 0, 2); SBq(0, 0, 3);
  SAq(0, srcA, 0, 0); SAq(0, srcA, 0, 2);
  SAq(0, srcA, 0, 1); SAq(0, srcA, 0, 3);
  asm volatile("s_waitcnt vmcnt(2)" ::: "memory");
  BAR();

#pragma unroll 1
  for (int mt = 0; mt < 12; ++mt) {
    const unsigned short* srcAn = srcA + 98304;  // next m-tile (+256 rows)

    TILE_STEADY(0, srcA, 1 * 64);
    TILE_STEADY(1, srcA, 2 * 64);
    TILE_STEADY(2, srcA, 3 * 64);
    TILE_STEADY(3, srcA, 4 * 64);
    TILE_STEADY(4, srcA, 5 * 64);
    if (mt < 11) {
      TILE_STEADY(5, srcAn, 0);   // stage (mt+1, kt=0) into buf0 (parity continuous)
    } else {
      // tail tile (11,5): no staging; drain A-odd before P2
      LDA(1, 0); LDB(1, 0, bf_lo);
      BAR(); LGKM0(); MM(0, 0, bf_lo); BAR();
      LDB(1, 1, bf_hi);
      BAR(); LGKM0(); MM(0, 1, bf_hi);
      asm volatile("s_waitcnt vmcnt(0)" ::: "memory");
      BAR();
      LDA(1, 1);
      BAR(); LGKM0(); MM(1, 1, bf_hi); MM(1, 0, bf_lo);
    }

    // epilogue for m-tile mt: pixel-major, column-routed per 16-col granule
    {
      const int m0 = mbase + mt * 256;
#pragma unroll
      for (int a = 0; a < 8; ++a) {
        int m = m0 + wr * 128 + a * 16 + g * 4;
#pragma unroll
        for (int b = 0; b < 4; ++b) {
          int nbase = n0 + wc * 64 + b * 16;
          if (nbase < 384) {
            unsigned short* cp = Cq + (size_t)m * 384 + nbase + r15;
#pragma unroll
            for (int r = 0; r < 4; ++r) cp[(size_t)r * 384] = f2bf(acc[a][b][r] * oscale);
          } else if (nbase < 1152) {
            unsigned short* cp = Ckv + (size_t)m * 768 + (nbase - 384) + r15;
#pragma unroll
            for (int r = 0; r < 4; ++r) cp[(size_t)r * 768] = f2bf(acc[a][b][r]);
          }
        }
      }
#pragma unroll
      for (int a = 0; a < 8; ++a)
#pragma unroll
        for (int b = 0; b < 4; ++b) acc[a][b] = zero4;
    }
    srcA = srcAn;
  }
#undef TILE_STEADY
#undef SAq
#undef SBq
#undef LDA
#undef LDB
#undef MM
#undef BAR
#undef LGKM0
}

// --------- out GEMM, BOTH sams in one dispatch (grid 3 x 576 x 2) ---------
__global__ __launch_bounds__(256) void gemm_out(
    const unsigned short* __restrict__ wfT,
    const unsigned short* __restrict__ ob0,
    const unsigned short* __restrict__ ob1,
    float* __restrict__ Cf,
    const float* __restrict__ bfu) {
  __shared__ __align__(16) unsigned short Lsh[3][8192];
  const int tid = threadIdx.x;
  const int lane = tid & 63;
  const int wid = tid >> 6, wr = wid >> 1, wc = wid & 1;

  const int gx = gridDim.x, gy = gridDim.y;
  const int nwg = gx * gy * gridDim.z;
  const int bid = blockIdx.x + (blockIdx.y + blockIdx.z * gy) * gx;
  const int chunk = nwg >> 3;
  const int l = (bid & 7) * chunk + (bid >> 3);
  const int bx = l % gx;
  const int by = (l / gx) % gy;
  const int s  = l / (gx * gy);

  const unsigned short* A  = wfT + (size_t)s * W2;
  const unsigned short* Bt = s ? ob1 : ob0;
  const float* bias = bfu + s * 384;

  const int m0 = bx * 128;
  const int n0 = by * 128;
  const int r15 = lane & 15, g = lane >> 4;

  const int u1 = tid + 256;
  const unsigned short* srcA0 = A + (size_t)(m0 + (tid >> 2)) * 384 + (((tid & 3) ^ ((tid >> 3) & 3)) << 3);
  const unsigned short* srcA1 = A + (size_t)(m0 + (u1 >> 2)) * 384 + (((u1 & 3) ^ ((u1 >> 3) & 3)) << 3);
  const unsigned short* srcB0 = Bt + (size_t)(n0 + (tid >> 2)) * 384 + (((tid & 3) ^ ((tid >> 3) & 3)) << 3);
  const unsigned short* srcB1 = Bt + (size_t)(n0 + (u1 >> 2)) * 384 + (((u1 & 3) ^ ((u1 >> 3) & 3)) << 3);
  const int wbase = (tid & ~63) * 8;

  f32x4 acc[4][4];
  f32x4 zero4 = {0.f, 0.f, 0.f, 0.f};
#pragma unroll
  for (int a = 0; a < 4; ++a)
#pragma unroll
    for (int b = 0; b < 4; ++b) acc[a][b] = zero4;

  const int swzr = (g ^ ((r15 >> 1) & 3)) << 3;

#define STAGE(buf, kt) do {                                  \
    int ke = (kt) * 32;                                      \
    gload16(srcA0 + ke, &Lsh[(buf)][wbase]);                 \
    gload16(srcA1 + ke, &Lsh[(buf)][2048 + wbase]);          \
    gload16(srcB0 + ke, &Lsh[(buf)][4096 + wbase]);          \
    gload16(srcB1 + ke, &Lsh[(buf)][6144 + wbase]);          \
  } while (0)

#define COMPUTE(buf) do {                                                       \
    bf16x8 af[4], bfv[4];                                                       \
    _Pragma("unroll")                                                           \
    for (int a = 0; a < 4; ++a)                                                 \
      af[a] = *(const bf16x8*)&Lsh[(buf)][(wr * 64 + a * 16 + r15) * 32 + swzr];\
    _Pragma("unroll")                                                           \
    for (int b = 0; b < 4; ++b)                                                 \
      bfv[b] = *(const bf16x8*)&Lsh[(buf)][4096 + (wc * 64 + b * 16 + r15) * 32 + swzr];\
    _Pragma("unroll")                                                           \
    for (int a = 0; a < 4; ++a)                                                 \
      _Pragma("unroll")                                                         \
      for (int b = 0; b < 4; ++b)                                               \
        acc[a][b] = __builtin_amdgcn_mfma_f32_16x16x32_bf16(af[a], bfv[b], acc[a][b], 0, 0, 0);\
  } while (0)

  STAGE(0, 0);
  STAGE(1, 1);
#pragma unroll
  for (int kt = 0; kt < 11; ++kt) {
    asm volatile("s_waitcnt vmcnt(4)" ::: "memory");
    __builtin_amdgcn_s_barrier();
    asm volatile("" ::: "memory");
    if (kt < 10) STAGE((kt + 2) % 3, kt + 2);
    COMPUTE(kt % 3);
  }
  __syncthreads();
  COMPUTE(11 % 3);
#undef STAGE
#undef COMPUTE

  int bb = n0 / HW;  // uniform per block
#pragma unroll
  for (int a = 0; a < 4; ++a) {
    int d = m0 + wr * 64 + a * 16 + g * 4;
#pragma unroll
    for (int b = 0; b < 4; ++b) {
      int n = n0 + wc * 64 + b * 16 + r15;
      int p = n - bb * HW;
#pragma unroll
      for (int r = 0; r < 4; ++r) {
        float v = acc[a][b][r] + bias[d + r];
        Cf[(((size_t)bb * CCH + (d + r)) * 2 + s) * HW + p] = v;
      }
    }
  }
}

// -------- windowed attention, BOTH sams in one dispatch (256,2,2) --------
__global__ __launch_bounds__(512, 2) void attn_kernel(
    const unsigned short* __restrict__ qb0,
    const unsigned short* __restrict__ qb1,
    const unsigned short* __restrict__ kvb0,
    const unsigned short* __restrict__ kvb1,
    const int* __restrict__ mask,
    unsigned short* __restrict__ ob0,
    unsigned short* __restrict__ ob1) {
  __shared__ __align__(16) unsigned short P[8][16][168];
  __shared__ int ptab[144];
  const int n = blockIdx.x, b = blockIdx.y, s = blockIdx.z;
  const unsigned short* q  = s ? qb1 : qb0;
  const unsigned short* kv = s ? kvb1 : kvb0;
  unsigned short* obuf = s ? ob1 : ob0;
  const int tid = threadIdx.x;
  const int h = tid >> 6, lane = tid & 63;
  const int c15 = lane & 15, g = lane >> 4;
  const int wy = n >> 4, wx = n & 15;
  const size_t rowbase = (size_t)b * HW;
  const int* mrow = mask + (size_t)(b * 2 + 1) * HW;

  if (tid < 144)
    ptab[tid] = (wy * 12 + tid / 12) * 192 + wx * 12 + tid % 12;

  for (int idx = lane; idx < 16 * 24; idx += 64)
    P[h][idx / 24][144 + (idx % 24)] = 0;
  __syncthreads();

  float biasv[9];
#pragma unroll
  for (int nt = 0; nt < 9; ++nt)
    biasv[nt] = (mrow[ptab[nt * 16 + c15]] == 0) ? -1e9f : 0.0f;

  bf16x8 zfrag = {0, 0, 0, 0, 0, 0, 0, 0};
  f32x4 zero4 = {0.f, 0.f, 0.f, 0.f};

  bf16x8 kf0[9], kf1[9];
#pragma unroll
  for (int nt = 0; nt < 9; ++nt) {
    const unsigned short* kp = kv + (rowbase + ptab[nt * 16 + c15]) * 768 + h * 48;
    kf0[nt] = *(const bf16x8*)(kp + g * 8);
    kf1[nt] = zfrag;
    if (g < 2) kf1[nt] = *(const bf16x8*)(kp + 32 + g * 8);
  }

  const unsigned short* vb = kv + rowbase * 768 + 384 + h * 48;
  bf16x8 vf[5][3];
#pragma unroll
  for (int ks = 0; ks < 5; ++ks) {
#pragma unroll
    for (int dt = 0; dt < 3; ++dt) {
      bf16x8 v = {0, 0, 0, 0, 0, 0, 0, 0};
#pragma unroll
      for (int j = 0; j < 8; ++j) {
        int sk = ks * 32 + g * 8 + j;
        if (sk < 144)
          v[j] = (short)vb[(size_t)ptab[sk] * 768 + dt * 16 + c15];
      }
      vf[ks][dt] = v;
    }
  }

  bf16x8 qf0, qf1;
  {
    const unsigned short* qp = q + (rowbase + ptab[c15]) * 384 + h * 48;
    qf0 = *(const bf16x8*)(qp + g * 8);
    qf1 = zfrag;
    if (g < 2) qf1 = *(const bf16x8*)(qp + 32 + g * 8);
  }

  for (int mt = 0; mt < 9; ++mt) {
    bf16x8 qn0 = zfrag, qn1 = zfrag;
    if (mt < 8) {
      const unsigned short* qp = q + (rowbase + ptab[(mt + 1) * 16 + c15]) * 384 + h * 48;
      qn0 = *(const bf16x8*)(qp + g * 8);
      if (g < 2) qn1 = *(const bf16x8*)(qp + 32 + g * 8);
    }

    float l4[4] = {0.f, 0.f, 0.f, 0.f};
    f32x4 oacc[3];
#pragma unroll
    for (int dt = 0; dt < 3; ++dt) oacc[dt] = zero4;

#pragma unroll
    for (int nt = 0; nt < 9; ++nt) {
      f32x4 sv = __builtin_amdgcn_mfma_f32_16x16x32_bf16(qf1, kf1[nt], zero4, 0, 0, 0);
      sv = __builtin_amdgcn_mfma_f32_16x16x32_bf16(qf0, kf0[nt], sv, 0, 0, 0);
#pragma unroll
      for (int r = 0; r < 4; ++r) {
        float pv = __expf(sv[r] + biasv[nt]);
        l4[r] += pv;
        P[h][g * 4 + r][nt * 16 + c15] = f2bf(pv);
      }
      if (nt & 1) {
        int ks = nt >> 1;
        bf16x8 pf = *(const bf16x8*)&P[h][c15][ks * 32 + g * 8];
#pragma unroll
        for (int dt = 0; dt < 3; ++dt)
          oacc[dt] = __builtin_amdgcn_mfma_f32_16x16x32_bf16(pf, vf[ks][dt], oacc[dt], 0, 0, 0);
      }
    }
    {
      bf16x8 pf = *(const bf16x8*)&P[h][c15][4 * 32 + g * 8];
#pragma unroll
      for (int dt = 0; dt < 3; ++dt)
        oacc[dt] = __builtin_amdgcn_mfma_f32_16x16x32_bf16(pf, vf[4][dt], oacc[dt], 0, 0, 0);
    }

#pragma unroll
    for (int st = 1; st < 16; st <<= 1)
#pragma unroll
      for (int r = 0; r < 4; ++r) l4[r] += __shfl_xor(l4[r], st, 64);

    float inv[4];
#pragma unroll
    for (int r = 0; r < 4; ++r) inv[r] = 1.0f / l4[r];
#pragma unroll
    for (int dt = 0; dt < 3; ++dt) {
#pragma unroll
      for (int r = 0; r < 4; ++r) {
        int so = mt * 16 + g * 4 + r;
        obuf[(rowbase + ptab[so]) * 384 + h * 48 + dt * 16 + c15] =
            f2bf(oacc[dt][r] * inv[r]);
      }
    }

    qf0 = qn0; qf1 = qn1;
  }
}

// ---------------- host ----------------
extern "C" void kernel_launch(void* const* d_in, const int* in_sizes, int n_in,
                              void* d_out, int out_size, void* d_ws, size_t ws_size,
                              hipStream_t stream) {
  const float* x    = (const float*)d_in[0];
  const int*   mask = (const int*)d_in[1];
  const float* wq1 = (const float*)d_in[2];
  const float* wk1 = (const float*)d_in[3];
  const float* wv1 = (const float*)d_in[4];
  const float* wo1 = (const float*)d_in[5];
  const float* wq2 = (const float*)d_in[6];
  const float* wk2 = (const float*)d_in[7];
  const float* wv2 = (const float*)d_in[8];
  const float* wo2 = (const float*)d_in[9];
  const float* pj1 = (const float*)d_in[10];
  const float* pj2 = (const float*)d_in[11];
  const float* bo1 = (const float*)d_in[12];
  const float* bo2 = (const float*)d_in[13];
  const float* pb1 = (const float*)d_in[14];
  const float* pb2 = (const float*)d_in[15];
  float* out = (float*)d_out;

  const float SCALE = 0.14433756729740643f;  // 48^-0.5, folded into Q

  char* ws = (char*)d_ws;
  size_t off = 0;
  unsigned short* wt   = (unsigned short*)(ws + off); off += (size_t)2 * WTF * 2;
  unsigned short* wfT  = (unsigned short*)(ws + off); off += (size_t)2 * W2 * 2;
  float*          bfu  = (float*)(ws + off);          off += (size_t)2 * 384 * 4;
  unsigned short* xbf  = (unsigned short*)(ws + off); off += (size_t)4 * HW * CCH * 2;
  size_t qsz = (size_t)NPIX * 384 * 2, kvsz = (size_t)NPIX * 768 * 2;
  unsigned short* qb0  = (unsigned short*)(ws + off); off += qsz;
  unsigned short* qb1  = (unsigned short*)(ws + off); off += qsz;
  unsigned short* kvb0 = (unsigned short*)(ws + off); off += kvsz;
  unsigned short* kvb1 = (unsigned short*)(ws + off); off += kvsz;
  unsigned short* ob0  = (unsigned short*)(ws + off); off += qsz;
  unsigned short* ob1  = (unsigned short*)(ws + off); off += qsz;
  if (ws_size < off) return;  // clean failure signal: output stays zero

  k_wt<<<dim3(576, 6), 256, 0, stream>>>(wq1, wk1, wv1, wq2, wk2, wv2, wt);
  k_pad<<<384, 256, 0, stream>>>(wt);
  k_wf<<<dim3(576, 2), 256, 0, stream>>>(wo1, pj1, wo2, pj2, wfT);
  k_bf<<<1, 768, 0, stream>>>(bo1, pj1, pb1, bo2, pj2, pb2, bfu);
  k_tx<<<dim3(576, 6, 4), 256, 0, stream>>>(x, xbf);

  gemm_qkv<<<dim3(5, 48), 512, 0, stream>>>(xbf, wt, qb0, qb1, kvb0, kvb1, SCALE);
  attn_kernel<<<dim3(256, 2, 2), 512, 0, stream>>>(qb0, qb1, kvb0, kvb1, mask, ob0, ob1);
  gemm_out<<<dim3(3, 576, 2), 256, 0, stream>>>(wfT, ob0, ob1, out, bfu);
}

// Round 15
// 657.602 us; speedup vs baseline: 1.4471x; 1.4471x over previous
//
#include <hip/hip_runtime.h>
#include <stdint.h>

typedef __attribute__((ext_vector_type(8))) short bf16x8;
typedef __attribute__((ext_vector_type(4))) float f32x4;

#define HW    36864   // 192*192
#define CCH   384
#define NPIX  73728   // 2 batches * HW
#define W2    147456  // 384*384
#define NPAD  1280    // padded QKV output channels (1152 -> 1280)
#define WTF   491520  // NPAD*384, per-frame weight panel elems

__device__ __forceinline__ unsigned short f2bf(float f) {
  unsigned u = __builtin_bit_cast(unsigned, f);
  u += 0x7FFFu + ((u >> 16) & 1u);
  return (unsigned short)(u >> 16);
}

typedef const unsigned int __attribute__((address_space(1)))* gas1_t;
typedef unsigned int __attribute__((address_space(3)))* las3_t;
__device__ __forceinline__ void gload16(const void* g, void* l) {
  __builtin_amdgcn_global_load_lds((gas1_t)g, (las3_t)l, 16, 0, 0);
}

// ---------------- prep kernels ----------------

// Per-frame padded weight panel: frame f rows = [wq_f | wk_{1-f} | wv_{1-f} | 0].
// grid y = 0..5: weights; y = 6: zero the pad rows 1152..1279 of both frames.
// (disjoint write regions: weights rows 0..1151, pad rows 1152..1279)
__global__ void k_wt(const float* __restrict__ w0, const float* __restrict__ w1,
                     const float* __restrict__ w2, const float* __restrict__ w3,
                     const float* __restrict__ w4, const float* __restrict__ w5,
                     unsigned short* __restrict__ wt) {
  int idx = blockIdx.x * 256 + threadIdx.x;   // 0..147455
  int w = blockIdx.y;
  if (w == 6) {  // pad rows: 2 frames x 128 rows x 384 = 98304 elems
    if (idx < 98304) {
      int f = idx / 49152, rem = idx % 49152;
      wt[(size_t)f * WTF + 1152 * 384 + rem] = 0;
    }
    return;
  }
  const float* W;
  switch (w) { case 0: W = w0; break; case 1: W = w1; break;
               case 2: W = w2; break; case 3: W = w3; break;
               case 4: W = w4; break; default: W = w5; break; }
  const int fmap[6]    = {0, 1, 1, 1, 0, 0};
  const int basemap[6] = {0, 384, 768, 0, 384, 768};
  int c = idx / 384, d = idx % 384;
  wt[(size_t)fmap[w] * WTF + (size_t)(basemap[w] + d) * 384 + c] =
      f2bf(W[(size_t)c * 384 + d]);
}

__global__ void k_wf(const float* __restrict__ wo1, const float* __restrict__ pj1,
                     const float* __restrict__ wo2, const float* __restrict__ pj2,
                     unsigned short* __restrict__ wfT) {
  int idx = blockIdx.x * 256 + threadIdx.x;
  int s = blockIdx.y;
  const float* wo = s ? wo2 : wo1;
  const float* pj = s ? pj2 : pj1;
  int d = idx / 384, e = idx % 384;
  float acc = 0.f;
  for (int c = 0; c < 384; ++c) acc += pj[d * 384 + c] * wo[e * 384 + c];
  wfT[(size_t)s * W2 + (size_t)d * 384 + e] = f2bf(acc);
}

__global__ void k_bf(const float* __restrict__ bo1, const float* __restrict__ pj1,
                     const float* __restrict__ pb1, const float* __restrict__ bo2,
                     const float* __restrict__ pj2, const float* __restrict__ pb2,
                     float* __restrict__ bfused) {
  int t = threadIdx.x;  // 0..767
  int s = t / 384, d = t % 384;
  const float* bo = s ? bo2 : bo1;
  const float* pj = s ? pj2 : pj1;
  const float* pb = s ? pb2 : pb1;
  float acc = pb[d];
  for (int c = 0; c < 384; ++c) acc += pj[d * 384 + c] * bo[c];
  bfused[t] = acc;
}

// xbf[t][b][p][c] = bf16( x[b][c][t][p] )
__global__ __launch_bounds__(256) void k_tx(const float* __restrict__ x,
                                            unsigned short* __restrict__ xbf) {
  __shared__ float tile[64][65];
  int p0 = blockIdx.x * 64;
  int c0 = blockIdx.y * 64;
  int bt = blockIdx.z;  // b*2 + t
  int b = bt >> 1, t = bt & 1;
  int tid = threadIdx.x;
  int cl = tid >> 2;
  int pq = (tid & 3) * 4;
  const float* src = x + (((size_t)b * CCH + (c0 + cl)) * 2 + t) * HW + p0;
#pragma unroll
  for (int i = 0; i < 4; ++i) {
    int p_l = pq + i * 16;
    float4 v = *reinterpret_cast<const float4*>(src + p_l);
    tile[cl][p_l + 0] = v.x; tile[cl][p_l + 1] = v.y;
    tile[cl][p_l + 2] = v.z; tile[cl][p_l + 3] = v.w;
  }
  __syncthreads();
  int pl = tid >> 2;
  int cq = (tid & 3) * 16;
  unsigned short* dst = xbf + ((size_t)(t * 2 + b) * HW + p0 + pl) * CCH + c0 + cq;
  bf16x8 o0, o1;
#pragma unroll
  for (int j = 0; j < 8; ++j) o0[j] = (short)f2bf(tile[cq + j][pl]);
#pragma unroll
  for (int j = 0; j < 8; ++j) o1[j] = (short)f2bf(tile[cq + 8 + j][pl]);
  *reinterpret_cast<bf16x8*>(dst) = o0;
  *reinterpret_cast<bf16x8*>(dst + 8) = o1;
}

// ---- QKV GEMM 256x256x64, m201-geometry 4-phase schedule, both frames ----
// (r12-proven: 219 us, MfmaUtil 28%, FETCH 86 MB. Short-lived blocks keep
// concurrent co-traversal -> L2/L3 panel sharing; do NOT make persistent.
// NOTE: P3 of each tile MUST re-read B lo (LDB(c,0)) before MM(1,0) — r14's
// hand-peeled tail dropped it and silently computed acc[4..7][0..1] vs B-hi.)
__global__ __launch_bounds__(512) void gemm_qkv(
    const unsigned short* __restrict__ xbf,
    const unsigned short* __restrict__ wt,
    unsigned short* __restrict__ qb0,
    unsigned short* __restrict__ qb1,
    unsigned short* __restrict__ kvb0,
    unsigned short* __restrict__ kvb1,
    float oscale) {
  __shared__ __align__(16) unsigned short Lsh[2][32768];  // A 0..16383 | B 16384..32767
  const int tid = threadIdx.x;
  const int lane = tid & 63;
  const int wid = tid >> 6;
  const int wr = wid >> 2, wc = wid & 3;   // 2 M-waves x 4 N-waves
  const int r15 = lane & 15, g = lane >> 4;
  const int rsw = r15 & 7;

  // XCD-aware swizzle (nwg = 2880)
  const int gx = gridDim.x;
  const int nwg = gx * gridDim.y;
  const int bid = blockIdx.x + blockIdx.y * gx;
  const int chunk = nwg >> 3;
  const int l = (bid & 7) * chunk + (bid >> 3);
  const int bx = l % gx, by = l / gx;

  const int f = (by >= 288) ? 1 : 0;
  const int m0 = (by - f * 288) * 256;
  const int n0 = bx * 256;

  const unsigned short* A  = xbf + (size_t)f * NPIX * 384;
  const unsigned short* Bt = wt + (size_t)f * WTF;
  unsigned short* Cq  = f ? qb1 : qb0;
  unsigned short* Ckv = f ? kvb0 : kvb1;

  const int gsl = (tid & 7) ^ ((tid >> 3) & 7);
  const unsigned short* srcA = A + (size_t)(m0 + (tid >> 3)) * 384 + gsl * 8;
  const unsigned short* srcB = Bt + (size_t)(n0 + (tid >> 3)) * 384 + gsl * 8;

  f32x4 acc[8][4];
  f32x4 zero4 = {0.f, 0.f, 0.f, 0.f};
#pragma unroll
  for (int a = 0; a < 8; ++a)
#pragma unroll
    for (int b = 0; b < 4; ++b) acc[a][b] = zero4;

#define SA(buf, kt, q) gload16(srcA + (size_t)(q) * 64 * 384 + (kt) * 64, \
                               &Lsh[(buf)][tid * 8 + (q) * 4096])
#define SB(buf, kt, q) gload16(srcB + (size_t)(q) * 64 * 384 + (kt) * 64, \
                               &Lsh[(buf)][16384 + tid * 8 + (q) * 4096])

  bf16x8 af[4][2], bf[2][2];
#define LDA(buf, mh) do {                                                        \
    _Pragma("unroll")                                                            \
    for (int a = 0; a < 4; ++a) {                                                \
      int row = wr * 128 + (mh) * 64 + a * 16 + r15;                             \
      af[a][0] = *(const bf16x8*)&Lsh[(buf)][row * 64 + ((0 + g) ^ rsw) * 8];    \
      af[a][1] = *(const bf16x8*)&Lsh[(buf)][row * 64 + ((4 + g) ^ rsw) * 8];    \
    } } while (0)
#define LDB(buf, nh) do {                                                        \
    _Pragma("unroll")                                                            \
    for (int b = 0; b < 2; ++b) {                                                \
      int row = wc * 64 + (nh) * 32 + b * 16 + r15;                              \
      bf[b][0] = *(const bf16x8*)&Lsh[(buf)][16384 + row * 64 + ((0 + g) ^ rsw) * 8];\
      bf[b][1] = *(const bf16x8*)&Lsh[(buf)][16384 + row * 64 + ((4 + g) ^ rsw) * 8];\
    } } while (0)
#define MM(mh, nh) do {                                                          \
    __builtin_amdgcn_s_setprio(1);                                               \
    _Pragma("unroll")                                                            \
    for (int a = 0; a < 4; ++a)                                                  \
      _Pragma("unroll")                                                          \
      for (int b = 0; b < 2; ++b) {                                              \
        acc[(mh)*4+a][(nh)*2+b] = __builtin_amdgcn_mfma_f32_16x16x32_bf16(       \
            af[a][0], bf[b][0], acc[(mh)*4+a][(nh)*2+b], 0, 0, 0);               \
        acc[(mh)*4+a][(nh)*2+b] = __builtin_amdgcn_mfma_f32_16x16x32_bf16(       \
            af[a][1], bf[b][1], acc[(mh)*4+a][(nh)*2+b], 0, 0, 0);               \
      }                                                                          \
    __builtin_amdgcn_s_setprio(0);                                               \
  } while (0)

#define BAR() __builtin_amdgcn_s_barrier()
#define LGKM0() asm volatile("s_waitcnt lgkmcnt(0)" ::: "memory")

  // Steady tile: stage next tile split across phases.
  // Ledger (entry: 2 A-odd loads of this tile in flight):
  //  P0 +SB(q0,q1)->4; P1 +SB(q2,q3)->6, vmcnt(4) retires A-odd(this);
  //  P2 +SA(q0,q2)->6; P3 +SA(q1,q3)->8, vmcnt(2) retires B+A-even(next).
#define TILE(kt, STG, W1STR, W3)                                              \
  do {                                                                        \
    const int c_ = (kt) & 1, s_ = c_ ^ 1;                                     \
    LDA(c_, 0); LDB(c_, 0);                                                   \
    if (STG) { SB(s_, (kt) + 1, 0); SB(s_, (kt) + 1, 1); }                    \
    BAR(); LGKM0(); MM(0, 0); BAR();                                          \
    LDB(c_, 1);                                                               \
    if (STG) { SB(s_, (kt) + 1, 2); SB(s_, (kt) + 1, 3); }                    \
    BAR(); LGKM0(); MM(0, 1);                                                 \
    asm volatile("s_waitcnt " W1STR ::: "memory");                            \
    BAR();                                                                    \
    LDA(c_, 1);                                                               \
    if (STG) { SA(s_, (kt) + 1, 0); SA(s_, (kt) + 1, 2); }                    \
    BAR(); LGKM0(); MM(1, 1); BAR();                                          \
    LDB(c_, 0);                                                               \
    if (STG) { SA(s_, (kt) + 1, 1); SA(s_, (kt) + 1, 3); }                    \
    BAR(); LGKM0(); MM(1, 0);                                                 \
    if (W3) { asm volatile("s_waitcnt vmcnt(2)" ::: "memory"); BAR(); }       \
  } while (0)

  // prologue: stage tile 0; order B q0..3, A-even, A-odd; leave A-odd in flight
  SB(0, 0, 0); SB(0, 0, 1); SB(0, 0, 2); SB(0, 0, 3);
  SA(0, 0, 0); SA(0, 0, 2);
  SA(0, 0, 1); SA(0, 0, 3);
  asm volatile("s_waitcnt vmcnt(2)" ::: "memory");
  BAR();

  TILE(0, 1, "vmcnt(4)", 1);
  TILE(1, 1, "vmcnt(4)", 1);
  TILE(2, 1, "vmcnt(4)", 1);
  TILE(3, 1, "vmcnt(4)", 1);
  TILE(4, 1, "vmcnt(4)", 1);
  TILE(5, 0, "vmcnt(0)", 0);   // tail: r12-exact macro path (keeps LDB(c,0) re-read)
#undef TILE
#undef SA
#undef SB
#undef LDA
#undef LDB
#undef MM
#undef BAR
#undef LGKM0

  // epilogue: pixel-major, column-routed per 16-col granule (boundaries %16==0)
#pragma unroll
  for (int a = 0; a < 8; ++a) {
    int m = m0 + wr * 128 + a * 16 + g * 4;
#pragma unroll
    for (int b = 0; b < 4; ++b) {
      int nbase = n0 + wc * 64 + b * 16;
      if (nbase < 384) {
        unsigned short* cp = Cq + (size_t)m * 384 + nbase + r15;
#pragma unroll
        for (int r = 0; r < 4; ++r) cp[(size_t)r * 384] = f2bf(acc[a][b][r] * oscale);
      } else if (nbase < 1152) {
        unsigned short* cp = Ckv + (size_t)m * 768 + (nbase - 384) + r15;
#pragma unroll
        for (int r = 0; r < 4; ++r) cp[(size_t)r * 768] = f2bf(acc[a][b][r]);
      }
    }
  }
}

// --------- out GEMM, BOTH sams in one dispatch (grid 3 x 576 x 2) ---------
__global__ __launch_bounds__(256) void gemm_out(
    const unsigned short* __restrict__ wfT,
    const unsigned short* __restrict__ ob0,
    const unsigned short* __restrict__ ob1,
    float* __restrict__ Cf,
    const float* __restrict__ bfu) {
  __shared__ __align__(16) unsigned short Lsh[3][8192];
  const int tid = threadIdx.x;
  const int lane = tid & 63;
  const int wid = tid >> 6, wr = wid >> 1, wc = wid & 1;

  const int gx = gridDim.x, gy = gridDim.y;
  const int nwg = gx * gy * gridDim.z;
  const int bid = blockIdx.x + (blockIdx.y + blockIdx.z * gy) * gx;
  const int chunk = nwg >> 3;
  const int l = (bid & 7) * chunk + (bid >> 3);
  const int bx = l % gx;
  const int by = (l / gx) % gy;
  const int s  = l / (gx * gy);

  const unsigned short* A  = wfT + (size_t)s * W2;
  const unsigned short* Bt = s ? ob1 : ob0;
  const float* bias = bfu + s * 384;

  const int m0 = bx * 128;
  const int n0 = by * 128;
  const int r15 = lane & 15, g = lane >> 4;

  const int u1 = tid + 256;
  const unsigned short* srcA0 = A + (size_t)(m0 + (tid >> 2)) * 384 + (((tid & 3) ^ ((tid >> 3) & 3)) << 3);
  const unsigned short* srcA1 = A + (size_t)(m0 + (u1 >> 2)) * 384 + (((u1 & 3) ^ ((u1 >> 3) & 3)) << 3);
  const unsigned short* srcB0 = Bt + (size_t)(n0 + (tid >> 2)) * 384 + (((tid & 3) ^ ((tid >> 3) & 3)) << 3);
  const unsigned short* srcB1 = Bt + (size_t)(n0 + (u1 >> 2)) * 384 + (((u1 & 3) ^ ((u1 >> 3) & 3)) << 3);
  const int wbase = (tid & ~63) * 8;

  f32x4 acc[4][4];
  f32x4 zero4 = {0.f, 0.f, 0.f, 0.f};
#pragma unroll
  for (int a = 0; a < 4; ++a)
#pragma unroll
    for (int b = 0; b < 4; ++b) acc[a][b] = zero4;

  const int swzr = (g ^ ((r15 >> 1) & 3)) << 3;

#define STAGE(buf, kt) do {                                  \
    int ke = (kt) * 32;                                      \
    gload16(srcA0 + ke, &Lsh[(buf)][wbase]);                 \
    gload16(srcA1 + ke, &Lsh[(buf)][2048 + wbase]);          \
    gload16(srcB0 + ke, &Lsh[(buf)][4096 + wbase]);          \
    gload16(srcB1 + ke, &Lsh[(buf)][6144 + wbase]);          \
  } while (0)

#define COMPUTE(buf) do {                                                       \
    bf16x8 af[4], bfv[4];                                                       \
    _Pragma("unroll")                                                           \
    for (int a = 0; a < 4; ++a)                                                 \
      af[a] = *(const bf16x8*)&Lsh[(buf)][(wr * 64 + a * 16 + r15) * 32 + swzr];\
    _Pragma("unroll")                                                           \
    for (int b = 0; b < 4; ++b)                                                 \
      bfv[b] = *(const bf16x8*)&Lsh[(buf)][4096 + (wc * 64 + b * 16 + r15) * 32 + swzr];\
    _Pragma("unroll")                                                           \
    for (int a = 0; a < 4; ++a)                                                 \
      _Pragma("unroll")                                                         \
      for (int b = 0; b < 4; ++b)                                               \
        acc[a][b] = __builtin_amdgcn_mfma_f32_16x16x32_bf16(af[a], bfv[b], acc[a][b], 0, 0, 0);\
  } while (0)

  STAGE(0, 0);
  STAGE(1, 1);
#pragma unroll
  for (int kt = 0; kt < 11; ++kt) {
    asm volatile("s_waitcnt vmcnt(4)" ::: "memory");
    __builtin_amdgcn_s_barrier();
    asm volatile("" ::: "memory");
    if (kt < 10) STAGE((kt + 2) % 3, kt + 2);
    COMPUTE(kt % 3);
  }
  __syncthreads();
  COMPUTE(11 % 3);
#undef STAGE
#undef COMPUTE

  int bb = n0 / HW;  // uniform per block
#pragma unroll
  for (int a = 0; a < 4; ++a) {
    int d = m0 + wr * 64 + a * 16 + g * 4;
#pragma unroll
    for (int b = 0; b < 4; ++b) {
      int n = n0 + wc * 64 + b * 16 + r15;
      int p = n - bb * HW;
#pragma unroll
      for (int r = 0; r < 4; ++r) {
        float v = acc[a][b][r] + bias[d + r];
        Cf[(((size_t)bb * CCH + (d + r)) * 2 + s) * HW + p] = v;
      }
    }
  }
}

// -------- windowed attention, BOTH sams in one dispatch (256,2,2) --------
__global__ __launch_bounds__(512, 2) void attn_kernel(
    const unsigned short* __restrict__ qb0,
    const unsigned short* __restrict__ qb1,
    const unsigned short* __restrict__ kvb0,
    const unsigned short* __restrict__ kvb1,
    const int* __restrict__ mask,
    unsigned short* __restrict__ ob0,
    unsigned short* __restrict__ ob1) {
  __shared__ __align__(16) unsigned short P[8][16][168];
  __shared__ int ptab[144];
  const int n = blockIdx.x, b = blockIdx.y, s = blockIdx.z;
  const unsigned short* q  = s ? qb1 : qb0;
  const unsigned short* kv = s ? kvb1 : kvb0;
  unsigned short* obuf = s ? ob1 : ob0;
  const int tid = threadIdx.x;
  const int h = tid >> 6, lane = tid & 63;
  const int c15 = lane & 15, g = lane >> 4;
  const int wy = n >> 4, wx = n & 15;
  const size_t rowbase = (size_t)b * HW;
  const int* mrow = mask + (size_t)(b * 2 + 1) * HW;

  if (tid < 144)
    ptab[tid] = (wy * 12 + tid / 12) * 192 + wx * 12 + tid % 12;

  for (int idx = lane; idx < 16 * 24; idx += 64)
    P[h][idx / 24][144 + (idx % 24)] = 0;
  __syncthreads();

  float biasv[9];
#pragma unroll
  for (int nt = 0; nt < 9; ++nt)
    biasv[nt] = (mrow[ptab[nt * 16 + c15]] == 0) ? -1e9f : 0.0f;

  bf16x8 zfrag = {0, 0, 0, 0, 0, 0, 0, 0};
  f32x4 zero4 = {0.f, 0.f, 0.f, 0.f};

  bf16x8 kf0[9], kf1[9];
#pragma unroll
  for (int nt = 0; nt < 9; ++nt) {
    const unsigned short* kp = kv + (rowbase + ptab[nt * 16 + c15]) * 768 + h * 48;
    kf0[nt] = *(const bf16x8*)(kp + g * 8);
    kf1[nt] = zfrag;
    if (g < 2) kf1[nt] = *(const bf16x8*)(kp + 32 + g * 8);
  }

  const unsigned short* vb = kv + rowbase * 768 + 384 + h * 48;
  bf16x8 vf[5][3];
#pragma unroll
  for (int ks = 0; ks < 5; ++ks) {
#pragma unroll
    for (int dt = 0; dt < 3; ++dt) {
      bf16x8 v = {0, 0, 0, 0, 0, 0, 0, 0};
#pragma unroll
      for (int j = 0; j < 8; ++j) {
        int sk = ks * 32 + g * 8 + j;
        if (sk < 144)
          v[j] = (short)vb[(size_t)ptab[sk] * 768 + dt * 16 + c15];
      }
      vf[ks][dt] = v;
    }
  }

  bf16x8 qf0, qf1;
  {
    const unsigned short* qp = q + (rowbase + ptab[c15]) * 384 + h * 48;
    qf0 = *(const bf16x8*)(qp + g * 8);
    qf1 = zfrag;
    if (g < 2) qf1 = *(const bf16x8*)(qp + 32 + g * 8);
  }

  for (int mt = 0; mt < 9; ++mt) {
    bf16x8 qn0 = zfrag, qn1 = zfrag;
    if (mt < 8) {
      const unsigned short* qp = q + (rowbase + ptab[(mt + 1) * 16 + c15]) * 384 + h * 48;
      qn0 = *(const bf16x8*)(qp + g * 8);
      if (g < 2) qn1 = *(const bf16x8*)(qp + 32 + g * 8);
    }

    float l4[4] = {0.f, 0.f, 0.f, 0.f};
    f32x4 oacc[3];
#pragma unroll
    for (int dt = 0; dt < 3; ++dt) oacc[dt] = zero4;

#pragma unroll
    for (int nt = 0; nt < 9; ++nt) {
      f32x4 sv = __builtin_amdgcn_mfma_f32_16x16x32_bf16(qf1, kf1[nt], zero4, 0, 0, 0);
      sv = __builtin_amdgcn_mfma_f32_16x16x32_bf16(qf0, kf0[nt], sv, 0, 0, 0);
#pragma unroll
      for (int r = 0; r < 4; ++r) {
        float pv = __expf(sv[r] + biasv[nt]);
        l4[r] += pv;
        P[h][g * 4 + r][nt * 16 + c15] = f2bf(pv);
      }
      if (nt & 1) {
        int ks = nt >> 1;
        bf16x8 pf = *(const bf16x8*)&P[h][c15][ks * 32 + g * 8];
#pragma unroll
        for (int dt = 0; dt < 3; ++dt)
          oacc[dt] = __builtin_amdgcn_mfma_f32_16x16x32_bf16(pf, vf[ks][dt], oacc[dt], 0, 0, 0);
      }
    }
    {
      bf16x8 pf = *(const bf16x8*)&P[h][c15][4 * 32 + g * 8];
#pragma unroll
      for (int dt = 0; dt < 3; ++dt)
        oacc[dt] = __builtin_amdgcn_mfma_f32_16x16x32_bf16(pf, vf[4][dt], oacc[dt], 0, 0, 0);
    }

#pragma unroll
    for (int st = 1; st < 16; st <<= 1)
#pragma unroll
      for (int r = 0; r < 4; ++r) l4[r] += __shfl_xor(l4[r], st, 64);

    float inv[4];
#pragma unroll
    for (int r = 0; r < 4; ++r) inv[r] = 1.0f / l4[r];
#pragma unroll
    for (int dt = 0; dt < 3; ++dt) {
#pragma unroll
      for (int r = 0; r < 4; ++r) {
        int so = mt * 16 + g * 4 + r;
        obuf[(rowbase + ptab[so]) * 384 + h * 48 + dt * 16 + c15] =
            f2bf(oacc[dt][r] * inv[r]);
      }
    }

    qf0 = qn0; qf1 = qn1;
  }
}

// ---------------- host ----------------
extern "C" void kernel_launch(void* const* d_in, const int* in_sizes, int n_in,
                              void* d_out, int out_size, void* d_ws, size_t ws_size,
                              hipStream_t stream) {
  const float* x    = (const float*)d_in[0];
  const int*   mask = (const int*)d_in[1];
  const float* wq1 = (const float*)d_in[2];
  const float* wk1 = (const float*)d_in[3];
  const float* wv1 = (const float*)d_in[4];
  const float* wo1 = (const float*)d_in[5];
  const float* wq2 = (const float*)d_in[6];
  const float* wk2 = (const float*)d_in[7];
  const float* wv2 = (const float*)d_in[8];
  const float* wo2 = (const float*)d_in[9];
  const float* pj1 = (const float*)d_in[10];
  const float* pj2 = (const float*)d_in[11];
  const float* bo1 = (const float*)d_in[12];
  const float* bo2 = (const float*)d_in[13];
  const float* pb1 = (const float*)d_in[14];
  const float* pb2 = (const float*)d_in[15];
  float* out = (float*)d_out;

  const float SCALE = 0.14433756729740643f;  // 48^-0.5, folded into Q

  char* ws = (char*)d_ws;
  size_t off = 0;
  unsigned short* wt   = (unsigned short*)(ws + off); off += (size_t)2 * WTF * 2;
  unsigned short* wfT  = (unsigned short*)(ws + off); off += (size_t)2 * W2 * 2;
  float*          bfu  = (float*)(ws + off);          off += (size_t)2 * 384 * 4;
  unsigned short* xbf  = (unsigned short*)(ws + off); off += (size_t)4 * HW * CCH * 2;
  size_t qsz = (size_t)NPIX * 384 * 2, kvsz = (size_t)NPIX * 768 * 2;
  unsigned short* qb0  = (unsigned short*)(ws + off); off += qsz;
  unsigned short* qb1  = (unsigned short*)(ws + off); off += qsz;
  unsigned short* kvb0 = (unsigned short*)(ws + off); off += kvsz;
  unsigned short* kvb1 = (unsigned short*)(ws + off); off += kvsz;
  unsigned short* ob0  = (unsigned short*)(ws + off); off += qsz;
  unsigned short* ob1  = (unsigned short*)(ws + off); off += qsz;
  if (ws_size < off) return;  // clean failure signal: output stays zero

  k_wt<<<dim3(576, 7), 256, 0, stream>>>(wq1, wk1, wv1, wq2, wk2, wv2, wt);
  k_wf<<<dim3(576, 2), 256, 0, stream>>>(wo1, pj1, wo2, pj2, wfT);
  k_bf<<<1, 768, 0, stream>>>(bo1, pj1, pb1, bo2, pj2, pb2, bfu);
  k_tx<<<dim3(576, 6, 4), 256, 0, stream>>>(x, xbf);

  gemm_qkv<<<dim3(5, 576), 512, 0, stream>>>(xbf, wt, qb0, qb1, kvb0, kvb1, SCALE);
  attn_kernel<<<dim3(256, 2, 2), 512, 0, stream>>>(qb0, qb1, kvb0, kvb1, mask, ob0, ob1);
  gemm_out<<<dim3(3, 576, 2), 256, 0, stream>>>(wfT, ob0, ob1, out, bfu);
}